// Round 4
// baseline (2781.258 us; speedup 1.0000x reference)
//
#include <hip/hip_runtime.h>
#include <math.h>

#define NP 512
#define TT 12

typedef float f32x4 __attribute__((ext_vector_type(4)));
typedef __bf16 bf16x8 __attribute__((ext_vector_type(8)));

// ws float offsets
#define OFF_CURABS 0        // [2][N*2] double buffer
#define OFF_A      2048     // [2][N*64] double buffer (h @ W1[32:96] + base)
#define OFF_WIHT   67584    // 128*256 transposed W_ih
#define OFF_WHHT   100352   // 64*256 transposed W_hh
#define OFF_BAR    116736   // 16 ints (12 used, one per step)
// total 116752 floats = 467 KB

__global__ __launch_bounds__(256) void init_k(
    const float* __restrict__ obs, const float* __restrict__ W_ih,
    const float* __restrict__ W_hh, float* __restrict__ ws) {
  int tid = blockIdx.x * 256 + threadIdx.x;   // 128 blocks -> 32768 threads
  if (tid < 1024) ws[OFF_CURABS + tid] = obs[7 * 1024 + tid];  // obs_traj_pos[-1]
  if (tid < 32768) {
    int k = tid >> 8, g = tid & 255;
    ws[OFF_WIHT + tid] = W_ih[g * 128 + k];
  }
  if (tid < 16384) {
    int k = tid >> 8, g = tid & 255;
    ws[OFF_WHHT + tid] = W_hh[g * 64 + k];
  }
  if (tid < 16) ((int*)(ws + OFF_BAR))[tid] = 0;   // barrier counters (re-zeroed every launch)
}

// One block per pedestrian, persistent over all 12 steps.
// Software grid barrier (graph-capture safe). Co-residency guaranteed:
// launch_bounds(256,2) => >=2 blocks/CU by regs; LDS 39.8KB => 4 blocks/CU.
__global__ __launch_bounds__(256, 2) void fused_k(
    const float* __restrict__ lastpos, const float* __restrict__ cc,
    const float* __restrict__ zz, const int* __restrict__ nei,
    const float* __restrict__ h0, const float* __restrict__ c0,
    const float* __restrict__ epsin,
    const float* __restrict__ W_in, const float* __restrict__ b_in,
    const float* __restrict__ b_ih, const float* __restrict__ b_hh,
    const float* __restrict__ Wl2p, const float* __restrict__ bl2p,
    const float* __restrict__ W_sp, const float* __restrict__ b_sp,
    const float* __restrict__ W1, const float* __restrict__ b1,
    const float* __restrict__ W2, const float* __restrict__ b2,
    float* __restrict__ out, float* __restrict__ ws) {
  __shared__ __align__(16) __bf16 h1buf[4][32 * 72];  // per-wave tiles
  __shared__ __align__(16) __bf16 W2T[64 * 72];
  __shared__ float absx[512], absy[512];
  __shared__ int   ml[512];
  __shared__ float wcl[128], bib[64], basev[64];
  __shared__ float red[4][64];
  __shared__ float hloc[64], csloc[64], ctxloc[64], prevp[2];
  __shared__ float emb[162], xpart[2][128], xvec[128], gl[256];

  int t = threadIdx.x;
  int b = blockIdx.x;
  int lane = t & 63, w = t >> 6;
  int quad = lane >> 4, col = lane & 15;
  int* bar = (int*)(ws + OFF_BAR);

  // ---- one-time init (block-local state + folded constants) ----
  if (t < 64) {
    hloc[t] = h0[b * 64 + t];
    csloc[t] = c0[b * 64 + t];
    ctxloc[t] = 0.f;
    float s = b1[t];
    for (int e = 0; e < 32; ++e) s = fmaf(b_sp[e], W1[e * 64 + t], s);
    basev[t] = s;
  }
  if (t < 2) prevp[t] = lastpos[b * 2 + t];
  if (t < 128) {
    int d = t >> 6, m = t & 63;
    float s = 0.f;
    for (int e = 0; e < 32; ++e) s = fmaf(W_sp[d * 32 + e], W1[e * 64 + m], s);
    wcl[t] = s;
  }
  for (int e = t; e < 4096; e += 256)
    W2T[(e & 63) * 72 + (e >> 6)] = (__bf16)W2[e];
  __syncthreads();

  // W2 MFMA B-fragments, held in registers for the whole kernel
  bf16x8 bf00 = *(const bf16x8*)&W2T[(0 * 16 + col) * 72 + 0 * 32 + quad * 8];
  bf16x8 bf01 = *(const bf16x8*)&W2T[(0 * 16 + col) * 72 + 1 * 32 + quad * 8];
  bf16x8 bf10 = *(const bf16x8*)&W2T[(1 * 16 + col) * 72 + 0 * 32 + quad * 8];
  bf16x8 bf11 = *(const bf16x8*)&W2T[(1 * 16 + col) * 72 + 1 * 32 + quad * 8];
  bf16x8 bf20 = *(const bf16x8*)&W2T[(2 * 16 + col) * 72 + 0 * 32 + quad * 8];
  bf16x8 bf21 = *(const bf16x8*)&W2T[(2 * 16 + col) * 72 + 1 * 32 + quad * 8];
  bf16x8 bf30 = *(const bf16x8*)&W2T[(3 * 16 + col) * 72 + 0 * 32 + quad * 8];
  bf16x8 bf31 = *(const bf16x8*)&W2T[(3 * 16 + col) * 72 + 1 * 32 + quad * 8];
  float b2v0 = b2[col], b2v1 = b2[16 + col], b2v2 = b2[32 + col], b2v3 = b2[48 + col];

  const float* wiht = ws + OFF_WIHT;
  const float* whht = ws + OFF_WHHT;

  for (int st = 0; st < TT; ++st) {
    int abuf = st & 1;
    float* Aab = ws + OFF_A + abuf * 32768;

    // ================= row phase (all state block-local) =================
    if (t < 162) {
      float v;
      if (t < 2)       v = prevp[t];
      else if (t < 66) v = cc[b * 64 + (t - 2)];
      else if (t < 98) v = zz[b * 32 + (t - 66)];
      else             v = ctxloc[t - 98];
      emb[t] = v;
    }
    __syncthreads();
    {   // x = relu(emb @ W_in + b_in), split-K 2 ways
      int k = t & 127, p = t >> 7;
      float a0 = 0.f, a1 = 0.f;
      int d = p;
      for (; d + 2 < 162; d += 4) {
        a0 = fmaf(emb[d],     W_in[d * 128 + k],       a0);
        a1 = fmaf(emb[d + 2], W_in[(d + 2) * 128 + k], a1);
      }
      if (d < 162) a0 = fmaf(emb[d], W_in[d * 128 + k], a0);
      xpart[p][k] = a0 + a1;
    }
    __syncthreads();
    if (t < 128) xvec[t] = fmaxf(xpart[0][t] + xpart[1][t] + b_in[t], 0.f);
    __syncthreads();
    {   // gates
      int g = t;
      float s0 = 0.f, s1 = 0.f, s2 = 0.f, s3 = 0.f;
      for (int kk = 0; kk < 128; kk += 4) {
        s0 = fmaf(xvec[kk],     wiht[kk * 256 + g],       s0);
        s1 = fmaf(xvec[kk + 1], wiht[(kk + 1) * 256 + g], s1);
        s2 = fmaf(xvec[kk + 2], wiht[(kk + 2) * 256 + g], s2);
        s3 = fmaf(xvec[kk + 3], wiht[(kk + 3) * 256 + g], s3);
      }
      for (int kk = 0; kk < 64; kk += 4) {
        s0 = fmaf(hloc[kk],     whht[kk * 256 + g],       s0);
        s1 = fmaf(hloc[kk + 1], whht[(kk + 1) * 256 + g], s1);
        s2 = fmaf(hloc[kk + 2], whht[(kk + 2) * 256 + g], s2);
        s3 = fmaf(hloc[kk + 3], whht[(kk + 3) * 256 + g], s3);
      }
      gl[g] = b_ih[g] + b_hh[g] + ((s0 + s1) + (s2 + s3));
    }
    __syncthreads();
    if (t < 64) {   // LSTM state update (in-place in LDS)
      float ig = gl[t], fg = gl[64 + t], gg = gl[128 + t], og = gl[192 + t];
      float is = 1.f / (1.f + expf(-ig));
      float fs = 1.f / (1.f + expf(-fg));
      float os = 1.f / (1.f + expf(-og));
      float cn = fs * csloc[t] + is * tanhf(gg);
      csloc[t] = cn;
      hloc[t] = os * tanhf(cn);
    }
    __syncthreads();
    if (t < 128) {  // A = h@W1[32:96]+base -> global (dbuf); B = h@W1[96:160] -> bib (LDS only)
      int which = t >> 6, m = t & 63;
      const float* wb = W1 + (32 + which * 64) * 64 + m;
      float s0 = 0.f, s1 = 0.f, s2 = 0.f, s3 = 0.f;
      for (int k = 0; k < 64; k += 4) {
        s0 = fmaf(hloc[k],     wb[k * 64],       s0);
        s1 = fmaf(hloc[k + 1], wb[(k + 1) * 64], s1);
        s2 = fmaf(hloc[k + 2], wb[(k + 2) * 64], s2);
        s3 = fmaf(hloc[k + 3], wb[(k + 3) * 64], s3);
      }
      float s = (s0 + s1) + (s2 + s3);
      if (which == 0) Aab[b * 64 + m] = s + basev[m];
      else            bib[m] = s;
    }

    // ================= grid barrier (software, per-step counter) =========
    __syncthreads();               // drains this block's global writes (vmcnt)
    if (t == 0) {
      __threadfence();             // release: L2 writeback, device visibility
      __hip_atomic_fetch_add(&bar[st], 1, __ATOMIC_ACQ_REL, __HIP_MEMORY_SCOPE_AGENT);
      while (__hip_atomic_load(&bar[st], __ATOMIC_ACQUIRE, __HIP_MEMORY_SCOPE_AGENT) < NP)
        __builtin_amdgcn_s_sleep(8);
      __threadfence();             // acquire: invalidate stale caches
    }
    __syncthreads();

    // ================= pool phase =================
    int rb = st & 1, wbuf = rb ^ 1;
    const float* curabs  = ws + OFF_CURABS + rb * 1024;
    float*       curabsw = ws + OFF_CURABS + wbuf * 1024;
    const int* neirow = nei + ((size_t)st * NP + b) * NP;
    {
      const float2* ca = (const float2*)curabs;
      for (int j = t; j < 512; j += 256) {
        float2 p = ca[j];
        absx[j] = p.x; absy[j] = p.y;
        ml[j] = neirow[j];
      }
    }
    __syncthreads();

    float px = absx[b], py = absy[b];
    float wcx = wcl[lane], wcy = wcl[64 + lane];
    float bi  = bib[lane];
    float vmax0 = 0.f, vmax1 = 0.f, vmax2 = 0.f, vmax3 = 0.f;
    __bf16* myh1 = h1buf[w];

    for (int c = 0; c < 4; ++c) {
      int jbase = w * 128 + c * 32;
      #pragma unroll 4
      for (int j = 0; j < 32; ++j) {
        int jg = jbase + j;
        float v = fmaf(px - absx[jg], wcx,
                  fmaf(py - absy[jg], wcy, Aab[jg * 64 + lane] + bi));
        myh1[j * 72 + lane] = (__bf16)fmaxf(v, 0.f);
      }
      #pragma unroll
      for (int js = 0; js < 2; ++js) {
        bf16x8 a0 = *(const bf16x8*)&myh1[(js * 16 + col) * 72 + 0 * 32 + quad * 8];
        bf16x8 a1 = *(const bf16x8*)&myh1[(js * 16 + col) * 72 + 1 * 32 + quad * 8];
        int rowb = jbase + js * 16 + quad * 4;
        bool mk0 = ml[rowb] > 0, mk1 = ml[rowb + 1] > 0,
             mk2 = ml[rowb + 2] > 0, mk3 = ml[rowb + 3] > 0;
        f32x4 acc;
        acc = (f32x4){0.f, 0.f, 0.f, 0.f};
        acc = __builtin_amdgcn_mfma_f32_16x16x32_bf16(a0, bf00, acc, 0, 0, 0);
        acc = __builtin_amdgcn_mfma_f32_16x16x32_bf16(a1, bf01, acc, 0, 0, 0);
        vmax0 = fmaxf(vmax0, mk0 ? acc[0] + b2v0 : 0.f);
        vmax0 = fmaxf(vmax0, mk1 ? acc[1] + b2v0 : 0.f);
        vmax0 = fmaxf(vmax0, mk2 ? acc[2] + b2v0 : 0.f);
        vmax0 = fmaxf(vmax0, mk3 ? acc[3] + b2v0 : 0.f);
        acc = (f32x4){0.f, 0.f, 0.f, 0.f};
        acc = __builtin_amdgcn_mfma_f32_16x16x32_bf16(a0, bf10, acc, 0, 0, 0);
        acc = __builtin_amdgcn_mfma_f32_16x16x32_bf16(a1, bf11, acc, 0, 0, 0);
        vmax1 = fmaxf(vmax1, mk0 ? acc[0] + b2v1 : 0.f);
        vmax1 = fmaxf(vmax1, mk1 ? acc[1] + b2v1 : 0.f);
        vmax1 = fmaxf(vmax1, mk2 ? acc[2] + b2v1 : 0.f);
        vmax1 = fmaxf(vmax1, mk3 ? acc[3] + b2v1 : 0.f);
        acc = (f32x4){0.f, 0.f, 0.f, 0.f};
        acc = __builtin_amdgcn_mfma_f32_16x16x32_bf16(a0, bf20, acc, 0, 0, 0);
        acc = __builtin_amdgcn_mfma_f32_16x16x32_bf16(a1, bf21, acc, 0, 0, 0);
        vmax2 = fmaxf(vmax2, mk0 ? acc[0] + b2v2 : 0.f);
        vmax2 = fmaxf(vmax2, mk1 ? acc[1] + b2v2 : 0.f);
        vmax2 = fmaxf(vmax2, mk2 ? acc[2] + b2v2 : 0.f);
        vmax2 = fmaxf(vmax2, mk3 ? acc[3] + b2v2 : 0.f);
        acc = (f32x4){0.f, 0.f, 0.f, 0.f};
        acc = __builtin_amdgcn_mfma_f32_16x16x32_bf16(a0, bf30, acc, 0, 0, 0);
        acc = __builtin_amdgcn_mfma_f32_16x16x32_bf16(a1, bf31, acc, 0, 0, 0);
        vmax3 = fmaxf(vmax3, mk0 ? acc[0] + b2v3 : 0.f);
        vmax3 = fmaxf(vmax3, mk1 ? acc[1] + b2v3 : 0.f);
        vmax3 = fmaxf(vmax3, mk2 ? acc[2] + b2v3 : 0.f);
        vmax3 = fmaxf(vmax3, mk3 ? acc[3] + b2v3 : 0.f);
      }
    }
    vmax0 = fmaxf(vmax0, __shfl_xor(vmax0, 16));
    vmax0 = fmaxf(vmax0, __shfl_xor(vmax0, 32));
    vmax1 = fmaxf(vmax1, __shfl_xor(vmax1, 16));
    vmax1 = fmaxf(vmax1, __shfl_xor(vmax1, 32));
    vmax2 = fmaxf(vmax2, __shfl_xor(vmax2, 16));
    vmax2 = fmaxf(vmax2, __shfl_xor(vmax2, 32));
    vmax3 = fmaxf(vmax3, __shfl_xor(vmax3, 16));
    vmax3 = fmaxf(vmax3, __shfl_xor(vmax3, 32));
    if (lane < 16) {
      red[w][0 * 16 + lane] = vmax0;
      red[w][1 * 16 + lane] = vmax1;
      red[w][2 * 16 + lane] = vmax2;
      red[w][3 * 16 + lane] = vmax3;
    }
    __syncthreads();
    if (t < 64) {
      float m4 = fmaxf(fmaxf(red[0][t], red[1][t]),
                       fmaxf(red[2][t], red[3][t]));
      ctxloc[t] = m4;
    }
    __syncthreads();
    if (t < 64) {   // epilogue: mu/logvar/pos for pedestrian b
      int l = t;
      float cl = ctxloc[l];
      float sc0 = cl * Wl2p[(32 + l) * 2 + 0];
      float sc1 = cl * Wl2p[(32 + l) * 2 + 1];
      float m0 = 0.f, m1 = 0.f, v0 = 0.f, v1 = 0.f;
      if (l < 32) {
        float hm = hloc[l];
        m0 = hm * Wl2p[l * 2 + 0]; m1 = hm * Wl2p[l * 2 + 1];
        float hv = hloc[32 + l];
        v0 = hv * Wl2p[l * 2 + 0]; v1 = hv * Wl2p[l * 2 + 1];
      }
      for (int off = 32; off >= 1; off >>= 1) {
        sc0 += __shfl_down(sc0, off);
        sc1 += __shfl_down(sc1, off);
        m0  += __shfl_down(m0,  off);
        m1  += __shfl_down(m1,  off);
        v0  += __shfl_down(v0,  off);
        v1  += __shfl_down(v1,  off);
      }
      if (l == 0) {
        float mu0 = m0 + sc0 + bl2p[0], mu1 = m1 + sc1 + bl2p[1];
        float lv0 = v0 + sc0 + bl2p[0], lv1 = v1 + sc1 + bl2p[1];
        float e0 = epsin[st * 1024 + b * 2 + 0];
        float e1 = epsin[st * 1024 + b * 2 + 1];
        float p0 = mu0 + e0 * expf(0.5f * lv0);
        float p1 = mu1 + e1 * expf(0.5f * lv1);
        out[st * 1024 + b * 2 + 0] = p0;
        out[st * 1024 + b * 2 + 1] = p1;
        out[12288 + st * 1024 + b * 2 + 0] = mu0;
        out[12288 + st * 1024 + b * 2 + 1] = mu1;
        out[24576 + st * 1024 + b * 2 + 0] = lv0;
        out[24576 + st * 1024 + b * 2 + 1] = lv1;
        curabsw[b * 2 + 0] = px + p0;
        curabsw[b * 2 + 1] = py + p1;
        prevp[0] = p0;
        prevp[1] = p1;
      }
    }
    __syncthreads();   // prevp/ctxloc ready for next step's row phase
  }
}

extern "C" void kernel_launch(void* const* d_in, const int* in_sizes, int n_in,
                              void* d_out, int out_size, void* d_ws, size_t ws_size,
                              hipStream_t stream) {
  const float* lastpos = (const float*)d_in[0];
  const float* cc      = (const float*)d_in[1];
  const float* zz      = (const float*)d_in[2];
  const float* obs     = (const float*)d_in[3];
  const int*   nei     = (const int*)d_in[4];
  const float* h0      = (const float*)d_in[6];
  const float* c0      = (const float*)d_in[7];
  const float* eps     = (const float*)d_in[8];
  const float* W_in    = (const float*)d_in[9];
  const float* b_in    = (const float*)d_in[10];
  const float* W_ih    = (const float*)d_in[11];
  const float* W_hh    = (const float*)d_in[12];
  const float* b_ih    = (const float*)d_in[13];
  const float* b_hh    = (const float*)d_in[14];
  const float* W_l2p   = (const float*)d_in[15];
  const float* b_l2p   = (const float*)d_in[16];
  const float* W_sp    = (const float*)d_in[17];
  const float* b_sp    = (const float*)d_in[18];
  const float* W1      = (const float*)d_in[19];
  const float* b1      = (const float*)d_in[20];
  const float* W2      = (const float*)d_in[21];
  const float* b2      = (const float*)d_in[22];
  float* out = (float*)d_out;
  float* ws  = (float*)d_ws;

  hipLaunchKernelGGL(init_k, dim3(128), dim3(256), 0, stream,
                     obs, W_ih, W_hh, ws);
  hipLaunchKernelGGL(fused_k, dim3(NP), dim3(256), 0, stream,
                     lastpos, cc, zz, nei, h0, c0, eps,
                     W_in, b_in, b_ih, b_hh, W_l2p, b_l2p, W_sp, b_sp,
                     W1, b1, W2, b2, out, ws);
}

// Round 6
// 394.470 us; speedup vs baseline: 7.0506x; 7.0506x over previous
//
#include <hip/hip_runtime.h>
#include <math.h>

#define NP 512
#define TT 12

typedef float f32x4 __attribute__((ext_vector_type(4)));
typedef __bf16 bf16x8 __attribute__((ext_vector_type(8)));

// ws float offsets
#define OFF_CURABS 0        // [2][N*2] double buffer
#define OFF_A      2048     // [2][N*64] double buffer (h @ W1[32:96] + base)
#define OFF_B      67584    // N*64 (h @ W1[96:160])
#define OFF_H      100352   // N*64
#define OFF_CS     133120   // N*64
#define OFF_WIHT   165888   // 128*256 transposed W_ih
#define OFF_WHHT   198656   // 64*256 transposed W_hh
#define OFF_WC     215040   // [2][64]  W_sp @ W1[0:32]
#define OFF_BASE   215168   // [64]     b1 + b_sp @ W1[0:32]
// total 215232 floats = 861 KB

__global__ __launch_bounds__(256) void init_k(
    const float* __restrict__ obs, const float* __restrict__ W_ih,
    const float* __restrict__ W_hh, const float* __restrict__ W_sp,
    const float* __restrict__ b_sp, const float* __restrict__ W1,
    const float* __restrict__ b1, float* __restrict__ ws) {
  int tid = blockIdx.x * 256 + threadIdx.x;   // 128 blocks -> 32768 threads
  if (tid < 1024) ws[OFF_CURABS + tid] = obs[7 * 1024 + tid];  // obs_traj_pos[-1]
  if (tid < 32768) {
    int k = tid >> 8, g = tid & 255;
    ws[OFF_WIHT + tid] = W_ih[g * 128 + k];
  }
  if (tid < 16384) {
    int k = tid >> 8, g = tid & 255;
    ws[OFF_WHHT + tid] = W_hh[g * 64 + k];
  }
  if (tid < 128) {
    int d = tid >> 6, m = tid & 63;
    float s = 0.f;
    for (int e = 0; e < 32; ++e) s = fmaf(W_sp[d * 32 + e], W1[e * 64 + m], s);
    ws[OFF_WC + tid] = s;
  }
  if (tid < 64) {
    float s = b1[tid];
    for (int e = 0; e < 32; ++e) s = fmaf(b_sp[e], W1[e * 64 + tid], s);
    ws[OFF_BASE + tid] = s;
  }
}

// Kernel s (s in [0,12]): pool(s-1) if s>0, then row(s) if s<12.
// One block per pedestrian. Kernel boundary = grid barrier.
// A double-buffered by parity: pool(s-1) reads A[(s-1)&1]; row(s) writes A[s&1].
__global__ __launch_bounds__(256) void step_k(
    const float* __restrict__ lastpos, const float* __restrict__ cc,
    const float* __restrict__ zz, const int* __restrict__ nei,
    const float* __restrict__ h0, const float* __restrict__ c0,
    const float* __restrict__ epsin,
    const float* __restrict__ W_in, const float* __restrict__ b_in,
    const float* __restrict__ b_ih, const float* __restrict__ b_hh,
    const float* __restrict__ Wl2p, const float* __restrict__ bl2p,
    const float* __restrict__ W1, const float* __restrict__ W2,
    const float* __restrict__ b2,
    float* __restrict__ out, float* __restrict__ ws, int s) {
  __shared__ __align__(16) __bf16 h1buf[4][32 * 72];  // per-wave tiles
  __shared__ __align__(16) __bf16 W2T[64 * 72];
  __shared__ float absx[512], absy[512];
  __shared__ int   ml[512];
  __shared__ float wcl[128], bib[64], basev[64];
  __shared__ float red[4][64];
  __shared__ float hloc[64], csloc[64], ctxloc[64], prevp[2];
  __shared__ float emb[162], xpart[2][128], xvec[128], gl[256];

  int t = threadIdx.x;
  int b = blockIdx.x;
  int lane = t & 63, w = t >> 6;
  int quad = lane >> 4, col = lane & 15;

  // ---- staging ----
  if (t < 64) {
    if (s == 0) { hloc[t] = h0[b * 64 + t]; csloc[t] = c0[b * 64 + t]; ctxloc[t] = 0.f; }
    else        { hloc[t] = ws[OFF_H + b * 64 + t]; csloc[t] = ws[OFF_CS + b * 64 + t]; }
    basev[t] = ws[OFF_BASE + t];
  } else if (t < 192) {
    wcl[t - 64] = ws[OFF_WC + (t - 64)];          // FIXED (was t-128: OOB + half-uninit)
  } else if (s > 0) {                              // t in [192,256)
    bib[t - 192] = ws[OFF_B + b * 64 + (t - 192)];
  }
  if (s == 0 && t < 2) prevp[t] = lastpos[b * 2 + t];
  if (s > 0) {
    for (int e = t; e < 4096; e += 256)
      W2T[(e & 63) * 72 + (e >> 6)] = (__bf16)W2[e];
  }
  __syncthreads();

  // ================= pool phase: st = s-1 =================
  if (s > 0) {
    int st = s - 1;
    bf16x8 bf00 = *(const bf16x8*)&W2T[(0 * 16 + col) * 72 + 0 * 32 + quad * 8];
    bf16x8 bf01 = *(const bf16x8*)&W2T[(0 * 16 + col) * 72 + 1 * 32 + quad * 8];
    bf16x8 bf10 = *(const bf16x8*)&W2T[(1 * 16 + col) * 72 + 0 * 32 + quad * 8];
    bf16x8 bf11 = *(const bf16x8*)&W2T[(1 * 16 + col) * 72 + 1 * 32 + quad * 8];
    bf16x8 bf20 = *(const bf16x8*)&W2T[(2 * 16 + col) * 72 + 0 * 32 + quad * 8];
    bf16x8 bf21 = *(const bf16x8*)&W2T[(2 * 16 + col) * 72 + 1 * 32 + quad * 8];
    bf16x8 bf30 = *(const bf16x8*)&W2T[(3 * 16 + col) * 72 + 0 * 32 + quad * 8];
    bf16x8 bf31 = *(const bf16x8*)&W2T[(3 * 16 + col) * 72 + 1 * 32 + quad * 8];
    float b2v0 = b2[col], b2v1 = b2[16 + col], b2v2 = b2[32 + col], b2v3 = b2[48 + col];

    int rb = st & 1, wbuf = rb ^ 1;
    const float* curabs  = ws + OFF_CURABS + rb * 1024;
    float*       curabsw = ws + OFF_CURABS + wbuf * 1024;
    const float* Aab = ws + OFF_A + rb * 32768;
    const int* neirow = nei + ((size_t)st * NP + b) * NP;
    {
      const float2* ca = (const float2*)curabs;
      for (int j = t; j < 512; j += 256) {
        float2 p = ca[j];
        absx[j] = p.x; absy[j] = p.y;
        ml[j] = neirow[j];
      }
    }
    __syncthreads();

    float px = absx[b], py = absy[b];
    float wcx = wcl[lane], wcy = wcl[64 + lane];
    float bi  = bib[lane];
    float vmax0 = 0.f, vmax1 = 0.f, vmax2 = 0.f, vmax3 = 0.f;
    __bf16* myh1 = h1buf[w];

    for (int c = 0; c < 4; ++c) {
      int jbase = w * 128 + c * 32;
      #pragma unroll 4
      for (int j = 0; j < 32; ++j) {
        int jg = jbase + j;
        float v = fmaf(px - absx[jg], wcx,
                  fmaf(py - absy[jg], wcy, Aab[jg * 64 + lane] + bi));
        myh1[j * 72 + lane] = (__bf16)fmaxf(v, 0.f);
      }
      #pragma unroll
      for (int js = 0; js < 2; ++js) {
        bf16x8 a0 = *(const bf16x8*)&myh1[(js * 16 + col) * 72 + 0 * 32 + quad * 8];
        bf16x8 a1 = *(const bf16x8*)&myh1[(js * 16 + col) * 72 + 1 * 32 + quad * 8];
        int rowb = jbase + js * 16 + quad * 4;
        bool mk0 = ml[rowb] > 0, mk1 = ml[rowb + 1] > 0,
             mk2 = ml[rowb + 2] > 0, mk3 = ml[rowb + 3] > 0;
        f32x4 acc;
        acc = (f32x4){0.f, 0.f, 0.f, 0.f};
        acc = __builtin_amdgcn_mfma_f32_16x16x32_bf16(a0, bf00, acc, 0, 0, 0);
        acc = __builtin_amdgcn_mfma_f32_16x16x32_bf16(a1, bf01, acc, 0, 0, 0);
        vmax0 = fmaxf(vmax0, mk0 ? acc[0] + b2v0 : 0.f);
        vmax0 = fmaxf(vmax0, mk1 ? acc[1] + b2v0 : 0.f);
        vmax0 = fmaxf(vmax0, mk2 ? acc[2] + b2v0 : 0.f);
        vmax0 = fmaxf(vmax0, mk3 ? acc[3] + b2v0 : 0.f);
        acc = (f32x4){0.f, 0.f, 0.f, 0.f};
        acc = __builtin_amdgcn_mfma_f32_16x16x32_bf16(a0, bf10, acc, 0, 0, 0);
        acc = __builtin_amdgcn_mfma_f32_16x16x32_bf16(a1, bf11, acc, 0, 0, 0);
        vmax1 = fmaxf(vmax1, mk0 ? acc[0] + b2v1 : 0.f);
        vmax1 = fmaxf(vmax1, mk1 ? acc[1] + b2v1 : 0.f);
        vmax1 = fmaxf(vmax1, mk2 ? acc[2] + b2v1 : 0.f);
        vmax1 = fmaxf(vmax1, mk3 ? acc[3] + b2v1 : 0.f);
        acc = (f32x4){0.f, 0.f, 0.f, 0.f};
        acc = __builtin_amdgcn_mfma_f32_16x16x32_bf16(a0, bf20, acc, 0, 0, 0);
        acc = __builtin_amdgcn_mfma_f32_16x16x32_bf16(a1, bf21, acc, 0, 0, 0);
        vmax2 = fmaxf(vmax2, mk0 ? acc[0] + b2v2 : 0.f);
        vmax2 = fmaxf(vmax2, mk1 ? acc[1] + b2v2 : 0.f);
        vmax2 = fmaxf(vmax2, mk2 ? acc[2] + b2v2 : 0.f);
        vmax2 = fmaxf(vmax2, mk3 ? acc[3] + b2v2 : 0.f);
        acc = (f32x4){0.f, 0.f, 0.f, 0.f};
        acc = __builtin_amdgcn_mfma_f32_16x16x32_bf16(a0, bf30, acc, 0, 0, 0);
        acc = __builtin_amdgcn_mfma_f32_16x16x32_bf16(a1, bf31, acc, 0, 0, 0);
        vmax3 = fmaxf(vmax3, mk0 ? acc[0] + b2v3 : 0.f);
        vmax3 = fmaxf(vmax3, mk1 ? acc[1] + b2v3 : 0.f);
        vmax3 = fmaxf(vmax3, mk2 ? acc[2] + b2v3 : 0.f);
        vmax3 = fmaxf(vmax3, mk3 ? acc[3] + b2v3 : 0.f);
      }
    }
    vmax0 = fmaxf(vmax0, __shfl_xor(vmax0, 16));
    vmax0 = fmaxf(vmax0, __shfl_xor(vmax0, 32));
    vmax1 = fmaxf(vmax1, __shfl_xor(vmax1, 16));
    vmax1 = fmaxf(vmax1, __shfl_xor(vmax1, 32));
    vmax2 = fmaxf(vmax2, __shfl_xor(vmax2, 16));
    vmax2 = fmaxf(vmax2, __shfl_xor(vmax2, 32));
    vmax3 = fmaxf(vmax3, __shfl_xor(vmax3, 16));
    vmax3 = fmaxf(vmax3, __shfl_xor(vmax3, 32));
    if (lane < 16) {
      red[w][0 * 16 + lane] = vmax0;
      red[w][1 * 16 + lane] = vmax1;
      red[w][2 * 16 + lane] = vmax2;
      red[w][3 * 16 + lane] = vmax3;
    }
    __syncthreads();
    if (t < 64) {
      float m4 = fmaxf(fmaxf(red[0][t], red[1][t]),
                       fmaxf(red[2][t], red[3][t]));
      ctxloc[t] = m4;
    }
    __syncthreads();
    if (t < 64) {   // epilogue: mu/logvar/pos for pedestrian b (uses h(st)=hloc)
      int l = t;
      float cl = ctxloc[l];
      float sc0 = cl * Wl2p[(32 + l) * 2 + 0];
      float sc1 = cl * Wl2p[(32 + l) * 2 + 1];
      float m0 = 0.f, m1 = 0.f, v0 = 0.f, v1 = 0.f;
      if (l < 32) {
        float hm = hloc[l];
        m0 = hm * Wl2p[l * 2 + 0]; m1 = hm * Wl2p[l * 2 + 1];
        float hv = hloc[32 + l];
        v0 = hv * Wl2p[l * 2 + 0]; v1 = hv * Wl2p[l * 2 + 1];
      }
      for (int off = 32; off >= 1; off >>= 1) {
        sc0 += __shfl_down(sc0, off);
        sc1 += __shfl_down(sc1, off);
        m0  += __shfl_down(m0,  off);
        m1  += __shfl_down(m1,  off);
        v0  += __shfl_down(v0,  off);
        v1  += __shfl_down(v1,  off);
      }
      if (l == 0) {
        float mu0 = m0 + sc0 + bl2p[0], mu1 = m1 + sc1 + bl2p[1];
        float lv0 = v0 + sc0 + bl2p[0], lv1 = v1 + sc1 + bl2p[1];
        float e0 = epsin[st * 1024 + b * 2 + 0];
        float e1 = epsin[st * 1024 + b * 2 + 1];
        float p0 = mu0 + e0 * expf(0.5f * lv0);
        float p1 = mu1 + e1 * expf(0.5f * lv1);
        out[st * 1024 + b * 2 + 0] = p0;
        out[st * 1024 + b * 2 + 1] = p1;
        out[12288 + st * 1024 + b * 2 + 0] = mu0;
        out[12288 + st * 1024 + b * 2 + 1] = mu1;
        out[24576 + st * 1024 + b * 2 + 0] = lv0;
        out[24576 + st * 1024 + b * 2 + 1] = lv1;
        curabsw[b * 2 + 0] = px + p0;
        curabsw[b * 2 + 1] = py + p1;
        prevp[0] = p0;
        prevp[1] = p1;
      }
    }
    __syncthreads();   // prevp/ctxloc ready for row phase
  }

  // ================= row phase: st = s =================
  if (s < TT) {
    if (t < 162) {
      float v;
      if (t < 2)       v = prevp[t];
      else if (t < 66) v = cc[b * 64 + (t - 2)];
      else if (t < 98) v = zz[b * 32 + (t - 66)];
      else             v = ctxloc[t - 98];
      emb[t] = v;
    }
    __syncthreads();
    {   // x = relu(emb @ W_in + b_in), split-K 2 ways
      int k = t & 127, p = t >> 7;
      float a0 = 0.f, a1 = 0.f;
      int d = p;
      for (; d + 2 < 162; d += 4) {
        a0 = fmaf(emb[d],     W_in[d * 128 + k],       a0);
        a1 = fmaf(emb[d + 2], W_in[(d + 2) * 128 + k], a1);
      }
      if (d < 162) a0 = fmaf(emb[d], W_in[d * 128 + k], a0);
      xpart[p][k] = a0 + a1;
    }
    __syncthreads();
    if (t < 128) xvec[t] = fmaxf(xpart[0][t] + xpart[1][t] + b_in[t], 0.f);
    __syncthreads();
    {   // gates
      int g = t;
      const float* wiht = ws + OFF_WIHT;
      const float* whht = ws + OFF_WHHT;
      float s0 = 0.f, s1 = 0.f, s2 = 0.f, s3 = 0.f;
      for (int kk = 0; kk < 128; kk += 4) {
        s0 = fmaf(xvec[kk],     wiht[kk * 256 + g],       s0);
        s1 = fmaf(xvec[kk + 1], wiht[(kk + 1) * 256 + g], s1);
        s2 = fmaf(xvec[kk + 2], wiht[(kk + 2) * 256 + g], s2);
        s3 = fmaf(xvec[kk + 3], wiht[(kk + 3) * 256 + g], s3);
      }
      for (int kk = 0; kk < 64; kk += 4) {
        s0 = fmaf(hloc[kk],     whht[kk * 256 + g],       s0);
        s1 = fmaf(hloc[kk + 1], whht[(kk + 1) * 256 + g], s1);
        s2 = fmaf(hloc[kk + 2], whht[(kk + 2) * 256 + g], s2);
        s3 = fmaf(hloc[kk + 3], whht[(kk + 3) * 256 + g], s3);
      }
      gl[g] = b_ih[g] + b_hh[g] + ((s0 + s1) + (s2 + s3));
    }
    __syncthreads();
    if (t < 64) {   // LSTM update; persist h,cs to ws for next kernel
      float ig = gl[t], fg = gl[64 + t], gg = gl[128 + t], og = gl[192 + t];
      float is = 1.f / (1.f + expf(-ig));
      float fs = 1.f / (1.f + expf(-fg));
      float os = 1.f / (1.f + expf(-og));
      float cn = fs * csloc[t] + is * tanhf(gg);
      float hv = os * tanhf(cn);
      hloc[t] = hv;
      ws[OFF_CS + b * 64 + t] = cn;
      ws[OFF_H + b * 64 + t] = hv;
    }
    __syncthreads();
    if (t < 128) {  // A(s) -> ws dbuf[s&1] (+base); B(s) -> ws
      int which = t >> 6, m = t & 63;
      const float* wb = W1 + (32 + which * 64) * 64 + m;
      float s0 = 0.f, s1 = 0.f, s2 = 0.f, s3 = 0.f;
      for (int k = 0; k < 64; k += 4) {
        s0 = fmaf(hloc[k],     wb[k * 64],       s0);
        s1 = fmaf(hloc[k + 1], wb[(k + 1) * 64], s1);
        s2 = fmaf(hloc[k + 2], wb[(k + 2) * 64], s2);
        s3 = fmaf(hloc[k + 3], wb[(k + 3) * 64], s3);
      }
      float sv = (s0 + s1) + (s2 + s3);
      if (which == 0) ws[OFF_A + (s & 1) * 32768 + b * 64 + m] = sv + basev[m];
      else            ws[OFF_B + b * 64 + m] = sv;
    }
  }
}

extern "C" void kernel_launch(void* const* d_in, const int* in_sizes, int n_in,
                              void* d_out, int out_size, void* d_ws, size_t ws_size,
                              hipStream_t stream) {
  const float* lastpos = (const float*)d_in[0];
  const float* cc      = (const float*)d_in[1];
  const float* zz      = (const float*)d_in[2];
  const float* obs     = (const float*)d_in[3];
  const int*   nei     = (const int*)d_in[4];
  const float* h0      = (const float*)d_in[6];
  const float* c0      = (const float*)d_in[7];
  const float* eps     = (const float*)d_in[8];
  const float* W_in    = (const float*)d_in[9];
  const float* b_in    = (const float*)d_in[10];
  const float* W_ih    = (const float*)d_in[11];
  const float* W_hh    = (const float*)d_in[12];
  const float* b_ih    = (const float*)d_in[13];
  const float* b_hh    = (const float*)d_in[14];
  const float* W_l2p   = (const float*)d_in[15];
  const float* b_l2p   = (const float*)d_in[16];
  const float* W_sp    = (const float*)d_in[17];
  const float* b_sp    = (const float*)d_in[18];
  const float* W1      = (const float*)d_in[19];
  const float* b1      = (const float*)d_in[20];
  const float* W2      = (const float*)d_in[21];
  const float* b2      = (const float*)d_in[22];
  float* out = (float*)d_out;
  float* ws  = (float*)d_ws;

  hipLaunchKernelGGL(init_k, dim3(128), dim3(256), 0, stream,
                     obs, W_ih, W_hh, W_sp, b_sp, W1, b1, ws);
  for (int s = 0; s <= TT; ++s) {
    hipLaunchKernelGGL(step_k, dim3(NP), dim3(256), 0, stream,
                       lastpos, cc, zz, nei, h0, c0, eps,
                       W_in, b_in, b_ih, b_hh, W_l2p, b_l2p,
                       W1, W2, b2, out, ws, s);
  }
}